// Round 9
// baseline (1464.514 us; speedup 1.0000x reference)
//
#include <hip/hip_runtime.h>
#include <hip/hip_bf16.h>

typedef unsigned int u32;
typedef unsigned short u16;

#define B_ 64
#define N_ 8192
#define DI 8
#define O_ 10
#define DO_ 16
#define OD 160          // O_*DO_
#define NCHUNK 32       // n per block; grid = 256 blocks = 1/CU
#define NPART 256       // partial buffers (= grid)  -- ws >= 5.3 MB proven
#define SROW 248        // s_lds row stride: 64*248*4 = 63488 B.  (1) pushes
                        // total LDS past 81920 B so max-blocks/CU = 1 ==> the
                        // scheduler targets 2 waves/SIMD ==> 256-VGPR budget
                        // (the R8 sinking fix);  (2) bank=(24*b4+c)%32 is an
                        // exact 2-way spread -> conflict-free.
#define VROW 162        // v_lds u16 row pad

static __device__ __forceinline__ float blo(u32 p) { return __uint_as_float(p << 16); }

template <int CTRL>
static __device__ __forceinline__ float dpp_add(float x) {
    int y = __builtin_amdgcn_update_dpp(0, __float_as_int(x), CTRL, 0xF, 0xF, true);
    return x + __int_as_float(y);
}
// Sum across the 16 lanes of each DPP row; result replicated to all 16 lanes.
static __device__ __forceinline__ float row16_sum(float x) {
    x = dpp_add<0xB1>(x);    // quad_perm(1,0,3,2): + lane^1
    x = dpp_add<0x4E>(x);    // quad_perm(2,3,0,1): + lane^2
    x = dpp_add<0x124>(x);   // row_ror:4  -> quad sums
    x = dpp_add<0x128>(x);   // row_ror:8  -> full row sum
    return x;
}

static __device__ __forceinline__ float dot8(const float4& a, const float4& b,
                                             const float4& x0, const float4& x1) {
    float s = 0.0f;
    s = fmaf(a.x, x0.x, s); s = fmaf(a.y, x0.y, s);
    s = fmaf(a.z, x0.z, s); s = fmaf(a.w, x0.w, s);
    s = fmaf(b.x, x1.x, s); s = fmaf(b.y, x1.y, s);
    s = fmaf(b.z, x1.z, s); s = fmaf(b.w, x1.w, s);
    return s;
}

// Opaque register barrier: forces v into VGPRs here; with the 256-VGPR budget
// (see SROW comment) the scheduler can now afford to keep them live.
static __device__ __forceinline__ void pin4(float4& v) {
    asm volatile("" : "+v"(v.x), "+v"(v.y), "+v"(v.z), "+v"(v.w));
}

// Lane mapping: lane = (b4 = lane>>4, c = lane&15).  Wave owns one n at a
// time; W row held in 80 VGPRs (lane c holds rows od = 16*oo + c).
// b-loop t=0..15: b = b4 + 4t, x prefetched one iteration ahead.
// PHASE 0: c_route = 0.1 uniform.  PHASE 1: logits via DPP row-reduce,
// softmax in-register, weighting reuses live u[] regs.
// TAIL 1: fp16 partial per block (proven).  TAIL 2: global atomics (fallback).
template <int PHASE, int TAIL>
__global__ __launch_bounds__(512, 2)
void caps_pass(const float* __restrict__ Xf, const float* __restrict__ Wf,
               const u16* __restrict__ Vb, float* __restrict__ Sout,
               _Float16* __restrict__ Sh) {
    __shared__ float s_lds[B_ * SROW];          // 63488 B
    __shared__ u16  v_lds[B_ * VROW];           // 20736 B (total 84224 -> 1 block/CU)

    const int tid = threadIdx.x;
    for (int i = tid; i < B_ * SROW; i += 512) s_lds[i] = 0.0f;
    if (PHASE > 0) {
        for (int i = tid; i < B_ * OD; i += 512) {
            int b = i / OD, od = i - b * OD;
            v_lds[b * VROW + od] = Vb[i];
        }
    }
    __syncthreads();

    const int lane = tid & 63;
    const int b4 = lane >> 4;                                 // 0..3
    const int c  = lane & 15;                                 // 0..15 (= d)
    const int w  = __builtin_amdgcn_readfirstlane(tid >> 6);  // wave 0..7

    #pragma unroll 1
    for (int k = 0; k < NCHUNK / 8; ++k) {
        const int n = blockIdx.x * NCHUNK + w + 8 * k;        // wave-uniform
        const float* wrow = Wf + (size_t)n * (OD * DI);

        // ---- W row -> 80 pinned VGPRs: 20 independent dwordx4 loads issue
        // back-to-back -> ONE latency window per n, not per t.
        float4 wA[O_], wB[O_];
        #pragma unroll
        for (int oo = 0; oo < O_; ++oo) {
            const float* p = wrow + (oo * DO_ + c) * DI;
            wA[oo] = *(const float4*)p;
            wB[oo] = *(const float4*)(p + 4);
        }
        #pragma unroll
        for (int oo = 0; oo < O_; ++oo) { pin4(wA[oo]); pin4(wB[oo]); }

        // ---- x prefetch pipeline: load t=0 before the loop
        const float* xp0 = Xf + ((size_t)b4 * N_ + n) * DI;
        float4 xa = *(const float4*)xp0;
        float4 xb = *(const float4*)(xp0 + 4);

        #pragma unroll 2
        for (int t = 0; t < 16; ++t) {
            const int b = b4 + 4 * t;
            const float4 cx0 = xa, cx1 = xb;
            if (t < 15) {   // prefetch next b's x while computing this one
                const float* xp = Xf + ((size_t)(b + 4) * N_ + n) * DI;
                xa = *(const float4*)xp;
                xb = *(const float4*)(xp + 4);
            }

            float u[O_];                       // u_hat[b, o=oo, d=c]
            #pragma unroll
            for (int oo = 0; oo < O_; ++oo) u[oo] = dot8(wA[oo], wB[oo], cx0, cx1);

            if (PHASE == 0) {
                #pragma unroll
                for (int oo = 0; oo < O_; ++oo)
                    atomicAdd(&s_lds[b * SROW + oo * DO_ + c], 0.1f * u[oo]);
            } else {
                // logits: t[o] = sum_d u_hat * v  (DPP reduce over 16 d-lanes)
                float tl[O_];
                #pragma unroll
                for (int oo = 0; oo < O_; ++oo) {
                    const float vv = blo((u32)v_lds[b * VROW + oo * DO_ + c]);
                    tl[oo] = row16_sum(u[oo] * vv);
                }
                // softmax over the 10 out-capsules (|t| small, no max-sub)
                float den = 0.0f;
                #pragma unroll
                for (int oo = 0; oo < O_; ++oo) { tl[oo] = __expf(tl[oo]); den += tl[oo]; }
                const float rinv = 1.0f / den;
                // weighting: reuse live u[] regs (no recompute)
                #pragma unroll
                for (int oo = 0; oo < O_; ++oo)
                    atomicAdd(&s_lds[b * SROW + oo * DO_ + c], (tl[oo] * rinv) * u[oo]);
            }
        }
    }
    __syncthreads();
    if (TAIL == 2) {
        for (int i = tid; i < B_ * OD; i += 512) {
            int bb = i / OD, od = i - bb * OD;
            atomicAdd(&Sout[i], s_lds[bb * SROW + od]);
        }
    } else {
        _Float16* my = Sh + (size_t)blockIdx.x * (B_ * OD);
        for (int i = tid; i < B_ * OD; i += 512) {
            int bb = i / OD, od = i - bb * OD;
            my[i] = (_Float16)s_lds[bb * SROW + od];
        }
    }
}

// Fused cross-block reduce + squash (norm over OUT-CAPSULE axis, per (b,d)).
// PHASE 0: V0f=v0 fp32, Vb=bf16(v0). PHASE 1: Vb=bf16(v0+v1). PHASE 2: out fp32.
template <int PHASE>
__global__ __launch_bounds__(192)
void caps_reduce_fin(const _Float16* __restrict__ Sp, int nparts,
                     float* __restrict__ V0f, u16* __restrict__ Vb,
                     float* __restrict__ out) {
    __shared__ float s_s[OD];
    __shared__ float s_scale[DO_];
    const int b = blockIdx.x;
    const int t = threadIdx.x;
    if (t < OD) {
        float acc = 0.0f;
        const _Float16* p0 = Sp + b * OD + t;
        #pragma unroll 8
        for (int p = 0; p < nparts; ++p) acc += (float)p0[(size_t)p * (B_ * OD)];
        s_s[t] = acc;
    }
    __syncthreads();
    if (t < DO_) {
        float norm = 0.0f;
        #pragma unroll
        for (int o = 0; o < O_; ++o) { float x = s_s[o * DO_ + t]; norm = fmaf(x, x, norm); }
        s_scale[t] = norm / (1.0f + norm) * rsqrtf(norm + 1e-9f);
    }
    __syncthreads();
    if (t < OD) {
        const float v = s_s[t] * s_scale[t & 15];
        const int idx = b * OD + t;
        if (PHASE == 0) {
            V0f[idx] = v;
            __hip_bfloat16 h = __float2bfloat16(v);
            Vb[idx] = *(const u16*)&h;
        } else if (PHASE == 1) {
            const float vs = V0f[idx] + v;
            __hip_bfloat16 h = __float2bfloat16(vs);
            Vb[idx] = *(const u16*)&h;
        } else {
            out[idx] = v;
        }
    }
}

// Finalize for the atomic fallback (also zeroes S for the next pass).
template <int PHASE>
__global__ __launch_bounds__(1024)
void caps_finalize(float* __restrict__ S, float* __restrict__ V0f,
                   u16* __restrict__ Vb, float* __restrict__ out) {
    const int tid = threadIdx.x;      // 1024 = 64 b * 16 d
    const int b = tid >> 4, d = tid & 15;
    float sv[O_];
    float norm = 0.0f;
    #pragma unroll
    for (int o = 0; o < O_; ++o) {
        sv[o] = S[b * OD + o * DO_ + d];
        norm = fmaf(sv[o], sv[o], norm);
    }
    const float scale = norm / (1.0f + norm) * rsqrtf(norm + 1e-9f);
    #pragma unroll
    for (int o = 0; o < O_; ++o) {
        const int idx = b * OD + o * DO_ + d;
        const float v = scale * sv[o];
        if (PHASE == 0) {
            V0f[idx] = v;
            __hip_bfloat16 h = __float2bfloat16(v);
            Vb[idx] = *(const u16*)&h;
            S[idx] = 0.0f;
        } else if (PHASE == 1) {
            const float vs = V0f[idx] + v;
            __hip_bfloat16 h = __float2bfloat16(vs);
            Vb[idx] = *(const u16*)&h;
            S[idx] = 0.0f;
        } else {
            out[idx] = v;
        }
    }
}

extern "C" void kernel_launch(void* const* d_in, const int* in_sizes, int n_in,
                              void* d_out, int out_size, void* d_ws, size_t ws_size,
                              hipStream_t stream) {
    const float* Xf = (const float*)d_in[0];   // x: [64, 8192, 8] fp32
    const float* Wf = (const float*)d_in[1];   // W: [1, 8192, 10, 16, 8] fp32
    float* out = (float*)d_out;

    const size_t velems = (size_t)B_ * OD;                   // 10240
    const size_t base = velems * 4 + velems * 2;             // V0f fp32 + Vb bf16
    const size_t need = base + (size_t)NPART * velems * 2;   // 5,304,320 B (proven fits)

    float* V0f = (float*)d_ws;
    u16* Vb = (u16*)(V0f + velems);
    const dim3 grid(N_ / NCHUNK), blk(512), rgrid(B_), rblk(192);

    if (ws_size >= need) {
        // fast path: fp16 per-block partials (proven)
        _Float16* P = (_Float16*)((char*)d_ws + base);
        caps_pass<0, 1><<<grid, blk, 0, stream>>>(Xf, Wf, nullptr, nullptr, P);
        caps_reduce_fin<0><<<rgrid, rblk, 0, stream>>>(P, NPART, V0f, Vb, nullptr);
        caps_pass<1, 1><<<grid, blk, 0, stream>>>(Xf, Wf, Vb, nullptr, P);
        caps_reduce_fin<1><<<rgrid, rblk, 0, stream>>>(P, NPART, V0f, Vb, nullptr);
        caps_pass<1, 1><<<grid, blk, 0, stream>>>(Xf, Wf, Vb, nullptr, P);
        caps_reduce_fin<2><<<rgrid, rblk, 0, stream>>>(P, NPART, nullptr, nullptr, out);
    } else {
        // fallback: global atomic accumulator (proven R3 structure)
        float* S = (float*)((char*)d_ws + base);
        const dim3 one(1), fblk(1024);
        hipMemsetAsync(S, 0, velems * sizeof(float), stream);
        caps_pass<0, 2><<<grid, blk, 0, stream>>>(Xf, Wf, nullptr, S, nullptr);
        caps_finalize<0><<<one, fblk, 0, stream>>>(S, V0f, Vb, nullptr);
        caps_pass<1, 2><<<grid, blk, 0, stream>>>(Xf, Wf, Vb, S, nullptr);
        caps_finalize<1><<<one, fblk, 0, stream>>>(S, V0f, Vb, nullptr);
        caps_pass<1, 2><<<grid, blk, 0, stream>>>(Xf, Wf, Vb, S, nullptr);
        caps_finalize<2><<<one, fblk, 0, stream>>>(S, nullptr, nullptr, out);
    }
}

// Round 10
// 367.062 us; speedup vs baseline: 3.9898x; 3.9898x over previous
//
#include <hip/hip_runtime.h>
#include <hip/hip_bf16.h>

typedef unsigned int u32;
typedef unsigned short u16;

#define B_ 64
#define N_ 8192
#define DI 8
#define O_ 10
#define DO_ 16
#define OD 160          // O_*DO_
#define NCHUNK 32       // n per block; grid = 256 blocks = 1/CU
#define NPART 256       // partial buffers (= grid) -- ws >= 5.3 MB proven R5-R9

static __device__ __forceinline__ float blo(u32 p) { return __uint_as_float(p << 16); }

template <int CTRL>
static __device__ __forceinline__ float dpp_add(float x) {
    int y = __builtin_amdgcn_update_dpp(0, __float_as_int(x), CTRL, 0xF, 0xF, true);
    return x + __int_as_float(y);
}
// Sum across each 16-lane DPP row; result replicated to all 16 lanes.
// (Proven correct R7-R9.)
static __device__ __forceinline__ float row16_sum(float x) {
    x = dpp_add<0xB1>(x);    // + lane^1
    x = dpp_add<0x4E>(x);    // + lane^2
    x = dpp_add<0x124>(x);   // row_ror:4
    x = dpp_add<0x128>(x);   // row_ror:8
    return x;
}

static __device__ __forceinline__ float dot8(const float4& a, const float4& b,
                                             const float4& x0, const float4& x1) {
    float s = 0.0f;
    s = fmaf(a.x, x0.x, s); s = fmaf(a.y, x0.y, s);
    s = fmaf(a.z, x0.z, s); s = fmaf(a.w, x0.w, s);
    s = fmaf(b.x, x1.x, s); s = fmaf(b.y, x1.y, s);
    s = fmaf(b.z, x1.z, s); s = fmaf(b.w, x1.w, s);
    return s;
}

// R10 structure: waves own disjoint b-ranges; n-accumulation in REGISTERS.
// Wave w covers b = 8w + b4 + 4t (t=0,1), lane=(b4=lane>>4, c=lane&15), and
// iterates ALL 32 n of the block.  ZERO LDS, ZERO atomics in this kernel --
// removes the 5120 ds_add wave-ops/block that R3-R9 all shared (the plateau).
// PHASE 0: c_route = 0.1.  PHASE 1: logits via DPP row-reduce + in-reg softmax
//          (rounds 1 & 2; v = v0 then v0+v1, since b2 = u.(v0+v1)).
// TAIL 1: fp16 partial per block (plain stores).  TAIL 2: global atomics.
template <int PHASE, int TAIL>
__global__ __launch_bounds__(512, 2)
void caps_pass(const float* __restrict__ Xf, const float* __restrict__ Wf,
               const u16* __restrict__ Vb, float* __restrict__ Sout,
               _Float16* __restrict__ Sh) {
    const int tid  = threadIdx.x;
    const int lane = tid & 63;
    const int b4   = lane >> 4;                                 // 0..3
    const int c    = lane & 15;                                 // 0..15 (= d)
    const int w    = __builtin_amdgcn_readfirstlane(tid >> 6);  // wave 0..7
    const int b0   = 8 * w + b4;                                // t=0 b; t=1 is b0+4

    // v for this wave's two b's -> 20 registers, loaded once from global.
    float vv0[O_], vv1[O_];
    if (PHASE > 0) {
        #pragma unroll
        for (int oo = 0; oo < O_; ++oo) {
            vv0[oo] = blo((u32)Vb[(size_t)b0 * OD + oo * DO_ + c]);
            vv1[oo] = blo((u32)Vb[(size_t)(b0 + 4) * OD + oo * DO_ + c]);
        }
    }

    float acc0[O_], acc1[O_];
    #pragma unroll
    for (int oo = 0; oo < O_; ++oo) { acc0[oo] = 0.0f; acc1[oo] = 0.0f; }

    const int nb = blockIdx.x * NCHUNK;

    // x prefetch pipeline (1 n ahead)
    const float* xp0 = Xf + ((size_t)b0 * N_ + nb) * DI;
    const float* xp1 = Xf + ((size_t)(b0 + 4) * N_ + nb) * DI;
    float4 xa0 = *(const float4*)xp0, xb0 = *(const float4*)(xp0 + 4);
    float4 xa1 = *(const float4*)xp1, xb1 = *(const float4*)(xp1 + 4);

    #pragma unroll 1
    for (int i = 0; i < NCHUNK; ++i) {
        const int n = nb + i;
        const float4 cxa0 = xa0, cxb0 = xb0, cxa1 = xa1, cxb1 = xb1;
        if (i < NCHUNK - 1) {
            const float* q0 = Xf + ((size_t)b0 * N_ + n + 1) * DI;
            const float* q1 = Xf + ((size_t)(b0 + 4) * N_ + n + 1) * DI;
            xa0 = *(const float4*)q0; xb0 = *(const float4*)(q0 + 4);
            xa1 = *(const float4*)q1; xb1 = *(const float4*)(q1 + 4);
        }

        // W row for this n: lane c reads rows od = 16*oo + c (32 B each);
        // short live ranges -> no residency fight; 8 waves share via L1/L2.
        const float* wrow = Wf + (size_t)n * (OD * DI);
        float u0[O_], u1[O_];
        #pragma unroll
        for (int oo = 0; oo < O_; ++oo) {
            const float* p = wrow + (oo * DO_ + c) * DI;
            const float4 a  = *(const float4*)p;
            const float4 bb = *(const float4*)(p + 4);
            u0[oo] = dot8(a, bb, cxa0, cxb0);
            u1[oo] = dot8(a, bb, cxa1, cxb1);
        }

        if (PHASE == 0) {
            #pragma unroll
            for (int oo = 0; oo < O_; ++oo) {
                acc0[oo] = fmaf(0.1f, u0[oo], acc0[oo]);
                acc1[oo] = fmaf(0.1f, u1[oo], acc1[oo]);
            }
        } else {
            // ---- t=0 capsule: logits -> softmax -> weighted accumulate
            float tl[O_];
            float den = 0.0f;
            #pragma unroll
            for (int oo = 0; oo < O_; ++oo) {
                tl[oo] = __expf(row16_sum(u0[oo] * vv0[oo]));
                den += tl[oo];
            }
            float rinv = 1.0f / den;
            #pragma unroll
            for (int oo = 0; oo < O_; ++oo)
                acc0[oo] = fmaf(tl[oo] * rinv, u0[oo], acc0[oo]);
            // ---- t=1 capsule
            den = 0.0f;
            #pragma unroll
            for (int oo = 0; oo < O_; ++oo) {
                tl[oo] = __expf(row16_sum(u1[oo] * vv1[oo]));
                den += tl[oo];
            }
            rinv = 1.0f / den;
            #pragma unroll
            for (int oo = 0; oo < O_; ++oo)
                acc1[oo] = fmaf(tl[oo] * rinv, u1[oo], acc1[oo]);
        }
    }

    // tail: each (b,od) owned by exactly one lane -> plain stores
    if (TAIL == 1) {
        _Float16* my = Sh + (size_t)blockIdx.x * (B_ * OD);
        #pragma unroll
        for (int oo = 0; oo < O_; ++oo) {
            my[(size_t)b0 * OD + oo * DO_ + c]       = (_Float16)acc0[oo];
            my[(size_t)(b0 + 4) * OD + oo * DO_ + c] = (_Float16)acc1[oo];
        }
    } else {
        #pragma unroll
        for (int oo = 0; oo < O_; ++oo) {
            atomicAdd(&Sout[(size_t)b0 * OD + oo * DO_ + c], acc0[oo]);
            atomicAdd(&Sout[(size_t)(b0 + 4) * OD + oo * DO_ + c], acc1[oo]);
        }
    }
}

// Fused cross-block reduce + squash (norm over OUT-CAPSULE axis, per (b,d)).
// PHASE 0: V0f=v0 fp32, Vb=bf16(v0). PHASE 1: Vb=bf16(v0+v1). PHASE 2: out fp32.
// (Proven correct R5-R9.)
template <int PHASE>
__global__ __launch_bounds__(192)
void caps_reduce_fin(const _Float16* __restrict__ Sp, int nparts,
                     float* __restrict__ V0f, u16* __restrict__ Vb,
                     float* __restrict__ out) {
    __shared__ float s_s[OD];
    __shared__ float s_scale[DO_];
    const int b = blockIdx.x;
    const int t = threadIdx.x;
    if (t < OD) {
        float acc = 0.0f;
        const _Float16* p0 = Sp + b * OD + t;
        #pragma unroll 8
        for (int p = 0; p < nparts; ++p) acc += (float)p0[(size_t)p * (B_ * OD)];
        s_s[t] = acc;
    }
    __syncthreads();
    if (t < DO_) {
        float norm = 0.0f;
        #pragma unroll
        for (int o = 0; o < O_; ++o) { float x = s_s[o * DO_ + t]; norm = fmaf(x, x, norm); }
        s_scale[t] = norm / (1.0f + norm) * rsqrtf(norm + 1e-9f);
    }
    __syncthreads();
    if (t < OD) {
        const float v = s_s[t] * s_scale[t & 15];
        const int idx = b * OD + t;
        if (PHASE == 0) {
            V0f[idx] = v;
            __hip_bfloat16 h = __float2bfloat16(v);
            Vb[idx] = *(const u16*)&h;
        } else if (PHASE == 1) {
            const float vs = V0f[idx] + v;
            __hip_bfloat16 h = __float2bfloat16(vs);
            Vb[idx] = *(const u16*)&h;
        } else {
            out[idx] = v;
        }
    }
}

// Finalize for the atomic fallback (also zeroes S for the next pass).
template <int PHASE>
__global__ __launch_bounds__(1024)
void caps_finalize(float* __restrict__ S, float* __restrict__ V0f,
                   u16* __restrict__ Vb, float* __restrict__ out) {
    const int tid = threadIdx.x;      // 1024 = 64 b * 16 d
    const int b = tid >> 4, d = tid & 15;
    float sv[O_];
    float norm = 0.0f;
    #pragma unroll
    for (int o = 0; o < O_; ++o) {
        sv[o] = S[b * OD + o * DO_ + d];
        norm = fmaf(sv[o], sv[o], norm);
    }
    const float scale = norm / (1.0f + norm) * rsqrtf(norm + 1e-9f);
    #pragma unroll
    for (int o = 0; o < O_; ++o) {
        const int idx = b * OD + o * DO_ + d;
        const float v = scale * sv[o];
        if (PHASE == 0) {
            V0f[idx] = v;
            __hip_bfloat16 h = __float2bfloat16(v);
            Vb[idx] = *(const u16*)&h;
            S[idx] = 0.0f;
        } else if (PHASE == 1) {
            const float vs = V0f[idx] + v;
            __hip_bfloat16 h = __float2bfloat16(vs);
            Vb[idx] = *(const u16*)&h;
            S[idx] = 0.0f;
        } else {
            out[idx] = v;
        }
    }
}

extern "C" void kernel_launch(void* const* d_in, const int* in_sizes, int n_in,
                              void* d_out, int out_size, void* d_ws, size_t ws_size,
                              hipStream_t stream) {
    const float* Xf = (const float*)d_in[0];   // x: [64, 8192, 8] fp32
    const float* Wf = (const float*)d_in[1];   // W: [1, 8192, 10, 16, 8] fp32
    float* out = (float*)d_out;

    const size_t velems = (size_t)B_ * OD;                   // 10240
    const size_t base = velems * 4 + velems * 2;             // V0f fp32 + Vb bf16
    const size_t need = base + (size_t)NPART * velems * 2;   // 5,304,320 B (proven fits)

    float* V0f = (float*)d_ws;
    u16* Vb = (u16*)(V0f + velems);
    const dim3 grid(N_ / NCHUNK), blk(512), rgrid(B_), rblk(192);

    if (ws_size >= need) {
        // fast path: fp16 per-block partials (proven)
        _Float16* P = (_Float16*)((char*)d_ws + base);
        caps_pass<0, 1><<<grid, blk, 0, stream>>>(Xf, Wf, nullptr, nullptr, P);
        caps_reduce_fin<0><<<rgrid, rblk, 0, stream>>>(P, NPART, V0f, Vb, nullptr);
        caps_pass<1, 1><<<grid, blk, 0, stream>>>(Xf, Wf, Vb, nullptr, P);
        caps_reduce_fin<1><<<rgrid, rblk, 0, stream>>>(P, NPART, V0f, Vb, nullptr);
        caps_pass<1, 1><<<grid, blk, 0, stream>>>(Xf, Wf, Vb, nullptr, P);
        caps_reduce_fin<2><<<rgrid, rblk, 0, stream>>>(P, NPART, nullptr, nullptr, out);
    } else {
        // fallback: global atomic accumulator
        float* S = (float*)((char*)d_ws + base);
        const dim3 one(1), fblk(1024);
        hipMemsetAsync(S, 0, velems * sizeof(float), stream);
        caps_pass<0, 2><<<grid, blk, 0, stream>>>(Xf, Wf, nullptr, S, nullptr);
        caps_finalize<0><<<one, fblk, 0, stream>>>(S, V0f, Vb, nullptr);
        caps_pass<1, 2><<<grid, blk, 0, stream>>>(Xf, Wf, Vb, S, nullptr);
        caps_finalize<1><<<one, fblk, 0, stream>>>(S, V0f, Vb, nullptr);
        caps_pass<1, 2><<<grid, blk, 0, stream>>>(Xf, Wf, Vb, S, nullptr);
        caps_finalize<2><<<one, fblk, 0, stream>>>(S, nullptr, nullptr, out);
    }
}

// Round 11
// 295.127 us; speedup vs baseline: 4.9623x; 1.2437x over previous
//
#include <hip/hip_runtime.h>
#include <hip/hip_bf16.h>

typedef unsigned int u32;
typedef unsigned short u16;

#define B_ 64
#define N_ 8192
#define DI 8
#define O_ 10
#define DO_ 16
#define OD 160          // O_*DO_
#define NCHUNK 32       // n per block; grid = 256 blocks = 1/CU
#define NPART 256       // partial buffers (= grid) -- ws >= 5.3 MB proven R5-R10
#define CHN 4           // n per LDS chunk (double-buffered: 8 chunks)
#define NCHK (NCHUNK / CHN)
#define WST 12          // dword stride per od-row in LDS: 48 B -> 16-B aligned
                        // b128 reads; banks (12c)%32: c,c+8 collide 2-way (free,
                        // m136), b4 groups same-address broadcast (free).
#define CHSZ (CHN * OD * WST)   // 7680 floats per chunk buffer

static __device__ __forceinline__ float blo(u32 p) { return __uint_as_float(p << 16); }

template <int CTRL>
static __device__ __forceinline__ float dpp_add(float x) {
    int y = __builtin_amdgcn_update_dpp(0, __float_as_int(x), CTRL, 0xF, 0xF, true);
    return x + __int_as_float(y);
}
// Sum across each 16-lane DPP row; result replicated to all 16 lanes. (Proven.)
static __device__ __forceinline__ float row16_sum(float x) {
    x = dpp_add<0xB1>(x);    // + lane^1
    x = dpp_add<0x4E>(x);    // + lane^2
    x = dpp_add<0x124>(x);   // row_ror:4
    x = dpp_add<0x128>(x);   // row_ror:8
    return x;
}

static __device__ __forceinline__ float dot8(const float4& a, const float4& b,
                                             const float4& x0, const float4& x1) {
    float s = 0.0f;
    s = fmaf(a.x, x0.x, s); s = fmaf(a.y, x0.y, s);
    s = fmaf(a.z, x0.z, s); s = fmaf(a.w, x0.w, s);
    s = fmaf(b.x, x1.x, s); s = fmaf(b.y, x1.y, s);
    s = fmaf(b.z, x1.z, s); s = fmaf(b.w, x1.w, s);
    return s;
}

// R10 structure (waves own b-ranges, register accumulation, zero atomics)
// + R11: W staged once into LDS (double-buffered 4-n chunks, stride-12 pad),
// compute reads via ds_read_b128 on the DS pipe instead of 8x-redundant VMEM.
template <int PHASE, int TAIL>
__global__ __launch_bounds__(512, 2)
void caps_pass(const float* __restrict__ Xf, const float* __restrict__ Wf,
               const u16* __restrict__ Vb, float* __restrict__ Sout,
               _Float16* __restrict__ Sh) {
    __shared__ float w_lds[2 * CHSZ];           // 61440 B

    const int tid  = threadIdx.x;
    const int lane = tid & 63;
    const int b4   = lane >> 4;                                 // 0..3
    const int c    = lane & 15;                                 // 0..15 (= d)
    const int w    = __builtin_amdgcn_readfirstlane(tid >> 6);  // wave 0..7
    const int b0   = 8 * w + b4;                                // t=0 b; t=1 is b0+4

    const int nb = blockIdx.x * NCHUNK;

    // staging map: 2560 float2 per chunk / 512 threads = 5 each (coalesced src)
    int srcoff[5], dstoff[5];
    #pragma unroll
    for (int k = 0; k < 5; ++k) {
        const int f2 = tid + k * 512;
        const int nloc = f2 / 640, rem = f2 - nloc * 640;
        const int od = rem >> 2, j2 = rem & 3;
        srcoff[k] = nloc * (OD * DI) + od * DI + j2 * 2;
        dstoff[k] = (nloc * OD + od) * WST + j2 * 2;
    }

    float2 st[5];
    {   // prologue: chunk 0 -> buf 0
        const float* src = Wf + (size_t)nb * (OD * DI);
        #pragma unroll
        for (int k = 0; k < 5; ++k) st[k] = *(const float2*)(src + srcoff[k]);
        #pragma unroll
        for (int k = 0; k < 5; ++k) *(float2*)&w_lds[dstoff[k]] = st[k];
    }
    __syncthreads();

    // v for this wave's two b's -> 20 registers (proven R10)
    float vv0[O_], vv1[O_];
    if (PHASE > 0) {
        #pragma unroll
        for (int oo = 0; oo < O_; ++oo) {
            vv0[oo] = blo((u32)Vb[(size_t)b0 * OD + oo * DO_ + c]);
            vv1[oo] = blo((u32)Vb[(size_t)(b0 + 4) * OD + oo * DO_ + c]);
        }
    }

    float acc0[O_], acc1[O_];
    #pragma unroll
    for (int oo = 0; oo < O_; ++oo) { acc0[oo] = 0.0f; acc1[oo] = 0.0f; }

    // x prefetch pipeline (1 n ahead), as R10
    const float* xp0 = Xf + ((size_t)b0 * N_ + nb) * DI;
    const float* xp1 = Xf + ((size_t)(b0 + 4) * N_ + nb) * DI;
    float4 xa0 = *(const float4*)xp0, xb0 = *(const float4*)(xp0 + 4);
    float4 xa1 = *(const float4*)xp1, xb1 = *(const float4*)(xp1 + 4);

    #pragma unroll 1
    for (int ch = 0; ch < NCHK; ++ch) {
        const float* wbuf = &w_lds[(ch & 1) * CHSZ];
        if (ch < NCHK - 1) {   // issue next chunk's global loads (overlap compute)
            const float* src = Wf + (size_t)(nb + (ch + 1) * CHN) * (OD * DI);
            #pragma unroll
            for (int k = 0; k < 5; ++k) st[k] = *(const float2*)(src + srcoff[k]);
        }

        #pragma unroll 1
        for (int nloc = 0; nloc < CHN; ++nloc) {
            const int i = ch * CHN + nloc;
            const int n = nb + i;
            const float4 cxa0 = xa0, cxb0 = xb0, cxa1 = xa1, cxb1 = xb1;
            if (i < NCHUNK - 1) {
                const float* q0 = Xf + ((size_t)b0 * N_ + n + 1) * DI;
                const float* q1 = Xf + ((size_t)(b0 + 4) * N_ + n + 1) * DI;
                xa0 = *(const float4*)q0; xb0 = *(const float4*)(q0 + 4);
                xa1 = *(const float4*)q1; xb1 = *(const float4*)(q1 + 4);
            }

            // W row from LDS: lane c reads rows od = 16*oo + c (b128 pairs)
            const float* wr = wbuf + nloc * (OD * WST);
            float u0[O_], u1[O_];
            #pragma unroll
            for (int oo = 0; oo < O_; ++oo) {
                const float* p = wr + (oo * DO_ + c) * WST;
                const float4 a  = *(const float4*)p;
                const float4 bb = *(const float4*)(p + 4);
                u0[oo] = dot8(a, bb, cxa0, cxb0);
                u1[oo] = dot8(a, bb, cxa1, cxb1);
            }

            if (PHASE == 0) {
                #pragma unroll
                for (int oo = 0; oo < O_; ++oo) {
                    acc0[oo] = fmaf(0.1f, u0[oo], acc0[oo]);
                    acc1[oo] = fmaf(0.1f, u1[oo], acc1[oo]);
                }
            } else {
                float tl[O_];
                float den = 0.0f;
                #pragma unroll
                for (int oo = 0; oo < O_; ++oo) {
                    tl[oo] = __expf(row16_sum(u0[oo] * vv0[oo]));
                    den += tl[oo];
                }
                float rinv = 1.0f / den;
                #pragma unroll
                for (int oo = 0; oo < O_; ++oo)
                    acc0[oo] = fmaf(tl[oo] * rinv, u0[oo], acc0[oo]);
                den = 0.0f;
                #pragma unroll
                for (int oo = 0; oo < O_; ++oo) {
                    tl[oo] = __expf(row16_sum(u1[oo] * vv1[oo]));
                    den += tl[oo];
                }
                rinv = 1.0f / den;
                #pragma unroll
                for (int oo = 0; oo < O_; ++oo)
                    acc1[oo] = fmaf(tl[oo] * rinv, u1[oo], acc1[oo]);
            }
        }

        if (ch < NCHK - 1) {   // write next chunk into the buffer just consumed
            float* dst = &w_lds[((ch + 1) & 1) * CHSZ];
            #pragma unroll
            for (int k = 0; k < 5; ++k) *(float2*)&dst[dstoff[k]] = st[k];
        }
        __syncthreads();
    }

    // tail: each (b,od) owned by exactly one lane -> plain stores (proven R10)
    if (TAIL == 1) {
        _Float16* my = Sh + (size_t)blockIdx.x * (B_ * OD);
        #pragma unroll
        for (int oo = 0; oo < O_; ++oo) {
            my[(size_t)b0 * OD + oo * DO_ + c]       = (_Float16)acc0[oo];
            my[(size_t)(b0 + 4) * OD + oo * DO_ + c] = (_Float16)acc1[oo];
        }
    } else {
        #pragma unroll
        for (int oo = 0; oo < O_; ++oo) {
            atomicAdd(&Sout[(size_t)b0 * OD + oo * DO_ + c], acc0[oo]);
            atomicAdd(&Sout[(size_t)(b0 + 4) * OD + oo * DO_ + c], acc1[oo]);
        }
    }
}

// Fused cross-block reduce + squash (norm over OUT-CAPSULE axis, per (b,d)).
// PHASE 0: V0f=v0 fp32, Vb=bf16(v0). PHASE 1: Vb=bf16(v0+v1). PHASE 2: out fp32.
// (Proven correct R5-R10.)
template <int PHASE>
__global__ __launch_bounds__(192)
void caps_reduce_fin(const _Float16* __restrict__ Sp, int nparts,
                     float* __restrict__ V0f, u16* __restrict__ Vb,
                     float* __restrict__ out) {
    __shared__ float s_s[OD];
    __shared__ float s_scale[DO_];
    const int b = blockIdx.x;
    const int t = threadIdx.x;
    if (t < OD) {
        float acc = 0.0f;
        const _Float16* p0 = Sp + b * OD + t;
        #pragma unroll 8
        for (int p = 0; p < nparts; ++p) acc += (float)p0[(size_t)p * (B_ * OD)];
        s_s[t] = acc;
    }
    __syncthreads();
    if (t < DO_) {
        float norm = 0.0f;
        #pragma unroll
        for (int o = 0; o < O_; ++o) { float x = s_s[o * DO_ + t]; norm = fmaf(x, x, norm); }
        s_scale[t] = norm / (1.0f + norm) * rsqrtf(norm + 1e-9f);
    }
    __syncthreads();
    if (t < OD) {
        const float v = s_s[t] * s_scale[t & 15];
        const int idx = b * OD + t;
        if (PHASE == 0) {
            V0f[idx] = v;
            __hip_bfloat16 h = __float2bfloat16(v);
            Vb[idx] = *(const u16*)&h;
        } else if (PHASE == 1) {
            const float vs = V0f[idx] + v;
            __hip_bfloat16 h = __float2bfloat16(vs);
            Vb[idx] = *(const u16*)&h;
        } else {
            out[idx] = v;
        }
    }
}

// Finalize for the atomic fallback (also zeroes S for the next pass).
template <int PHASE>
__global__ __launch_bounds__(1024)
void caps_finalize(float* __restrict__ S, float* __restrict__ V0f,
                   u16* __restrict__ Vb, float* __restrict__ out) {
    const int tid = threadIdx.x;      // 1024 = 64 b * 16 d
    const int b = tid >> 4, d = tid & 15;
    float sv[O_];
    float norm = 0.0f;
    #pragma unroll
    for (int o = 0; o < O_; ++o) {
        sv[o] = S[b * OD + o * DO_ + d];
        norm = fmaf(sv[o], sv[o], norm);
    }
    const float scale = norm / (1.0f + norm) * rsqrtf(norm + 1e-9f);
    #pragma unroll
    for (int o = 0; o < O_; ++o) {
        const int idx = b * OD + o * DO_ + d;
        const float v = scale * sv[o];
        if (PHASE == 0) {
            V0f[idx] = v;
            __hip_bfloat16 h = __float2bfloat16(v);
            Vb[idx] = *(const u16*)&h;
            S[idx] = 0.0f;
        } else if (PHASE == 1) {
            const float vs = V0f[idx] + v;
            __hip_bfloat16 h = __float2bfloat16(vs);
            Vb[idx] = *(const u16*)&h;
            S[idx] = 0.0f;
        } else {
            out[idx] = v;
        }
    }
}

extern "C" void kernel_launch(void* const* d_in, const int* in_sizes, int n_in,
                              void* d_out, int out_size, void* d_ws, size_t ws_size,
                              hipStream_t stream) {
    const float* Xf = (const float*)d_in[0];   // x: [64, 8192, 8] fp32
    const float* Wf = (const float*)d_in[1];   // W: [1, 8192, 10, 16, 8] fp32
    float* out = (float*)d_out;

    const size_t velems = (size_t)B_ * OD;                   // 10240
    const size_t base = velems * 4 + velems * 2;             // V0f fp32 + Vb bf16
    const size_t need = base + (size_t)NPART * velems * 2;   // 5,304,320 B (proven fits)

    float* V0f = (float*)d_ws;
    u16* Vb = (u16*)(V0f + velems);
    const dim3 grid(N_ / NCHUNK), blk(512), rgrid(B_), rblk(192);

    if (ws_size >= need) {
        // fast path: fp16 per-block partials (proven)
        _Float16* P = (_Float16*)((char*)d_ws + base);
        caps_pass<0, 1><<<grid, blk, 0, stream>>>(Xf, Wf, nullptr, nullptr, P);
        caps_reduce_fin<0><<<rgrid, rblk, 0, stream>>>(P, NPART, V0f, Vb, nullptr);
        caps_pass<1, 1><<<grid, blk, 0, stream>>>(Xf, Wf, Vb, nullptr, P);
        caps_reduce_fin<1><<<rgrid, rblk, 0, stream>>>(P, NPART, V0f, Vb, nullptr);
        caps_pass<1, 1><<<grid, blk, 0, stream>>>(Xf, Wf, Vb, nullptr, P);
        caps_reduce_fin<2><<<rgrid, rblk, 0, stream>>>(P, NPART, nullptr, nullptr, out);
    } else {
        // fallback: global atomic accumulator
        float* S = (float*)((char*)d_ws + base);
        const dim3 one(1), fblk(1024);
        hipMemsetAsync(S, 0, velems * sizeof(float), stream);
        caps_pass<0, 2><<<grid, blk, 0, stream>>>(Xf, Wf, nullptr, S, nullptr);
        caps_finalize<0><<<one, fblk, 0, stream>>>(S, V0f, Vb, nullptr);
        caps_pass<1, 2><<<grid, blk, 0, stream>>>(Xf, Wf, Vb, S, nullptr);
        caps_finalize<1><<<one, fblk, 0, stream>>>(S, V0f, Vb, nullptr);
        caps_pass<1, 2><<<grid, blk, 0, stream>>>(Xf, Wf, Vb, S, nullptr);
        caps_finalize<2><<<one, fblk, 0, stream>>>(S, nullptr, nullptr, out);
    }
}